// Round 1
// baseline (1783.823 us; speedup 1.0000x reference)
//
#include <hip/hip_runtime.h>

#define DM 1024

__device__ __forceinline__ float4 ldg4(const float* p) {
    return *reinterpret_cast<const float4*>(p);
}

// ---------------------------------------------------------------------------
// Generic 128x128-tile f32 GEMM, N=K=1024 fixed, M=4096 rows.
// C = act(A@W + b [+ A2@W2 + b2]); row mapping handles the 1025-row inputs:
// global row r -> source row (r>>10)*astride + (r&1023) + aoff.
// ACT: 0=none, 1=leaky_relu(0.2). 256 threads, 8x8 micro-tile in 4+4 chunks
// (rows ty*4 / ty*4+64, cols tx*4 / tx*4+64) so all ds_read_b128 are <=2-way
// bank aliased (free). As is stored k-major with stride 132 (16B aligned,
// spreads the transposed scalar stores across banks).
// ---------------------------------------------------------------------------
template<int ACT, bool DUAL>
__global__ __launch_bounds__(256) void gemm_k(
    const float* __restrict__ A, const float* __restrict__ A2,
    const float* __restrict__ W, const float* __restrict__ W2,
    const float* __restrict__ bias1, const float* __restrict__ bias2,
    float* __restrict__ C, int astride, int aoff)
{
    __shared__ float As [16][132];
    __shared__ float Ws [16][132];
    __shared__ float As2[DUAL ? 16 : 1][132];
    __shared__ float Ws2[DUAL ? 16 : 1][132];

    const int t  = threadIdx.x;
    const int tx = t & 15, ty = t >> 4;
    const int bm = blockIdx.x >> 3;   // 32 M-tiles
    const int bn = blockIdx.x & 7;    // 8 N-tiles

    // A-tile load slots: 128 rows x 16 k = 512 float4, 2 per thread
    const int row0 = t >> 2, kq0 = t & 3;
    const int row1 = row0 + 64;
    const int gr0 = bm * 128 + row0, gr1 = bm * 128 + row1;
    const size_t aof0 = ((size_t)(gr0 >> 10) * astride + (gr0 & 1023) + aoff) * DM;
    const size_t aof1 = ((size_t)(gr1 >> 10) * astride + (gr1 & 1023) + aoff) * DM;
    // W-tile load slots: 16 k-rows x 32 float4
    const int wk0 = t >> 5, wc0 = t & 31;
    const int wk1 = wk0 + 8;

    float acc[8][8] = {};

    for (int kt = 0; kt < 64; ++kt) {
        const int k0 = kt * 16;
        float4 av0 = ldg4(A + aof0 + k0 + kq0 * 4);
        float4 av1 = ldg4(A + aof1 + k0 + kq0 * 4);
        float4 wv0 = ldg4(W + (size_t)(k0 + wk0) * DM + bn * 128 + wc0 * 4);
        float4 wv1 = ldg4(W + (size_t)(k0 + wk1) * DM + bn * 128 + wc0 * 4);
        float4 av20, av21, wv20, wv21;
        if constexpr (DUAL) {
            av20 = ldg4(A2 + aof0 + k0 + kq0 * 4);
            av21 = ldg4(A2 + aof1 + k0 + kq0 * 4);
            wv20 = ldg4(W2 + (size_t)(k0 + wk0) * DM + bn * 128 + wc0 * 4);
            wv21 = ldg4(W2 + (size_t)(k0 + wk1) * DM + bn * 128 + wc0 * 4);
        }
        __syncthreads();   // previous tile's readers done
        As[kq0*4+0][row0] = av0.x; As[kq0*4+1][row0] = av0.y;
        As[kq0*4+2][row0] = av0.z; As[kq0*4+3][row0] = av0.w;
        As[kq0*4+0][row1] = av1.x; As[kq0*4+1][row1] = av1.y;
        As[kq0*4+2][row1] = av1.z; As[kq0*4+3][row1] = av1.w;
        *reinterpret_cast<float4*>(&Ws[wk0][wc0*4]) = wv0;
        *reinterpret_cast<float4*>(&Ws[wk1][wc0*4]) = wv1;
        if constexpr (DUAL) {
            As2[kq0*4+0][row0] = av20.x; As2[kq0*4+1][row0] = av20.y;
            As2[kq0*4+2][row0] = av20.z; As2[kq0*4+3][row0] = av20.w;
            As2[kq0*4+0][row1] = av21.x; As2[kq0*4+1][row1] = av21.y;
            As2[kq0*4+2][row1] = av21.z; As2[kq0*4+3][row1] = av21.w;
            *reinterpret_cast<float4*>(&Ws2[wk0][wc0*4]) = wv20;
            *reinterpret_cast<float4*>(&Ws2[wk1][wc0*4]) = wv21;
        }
        __syncthreads();

        #pragma unroll
        for (int kk = 0; kk < 16; ++kk) {
            float4 a0 = *reinterpret_cast<const float4*>(&As[kk][ty*4]);
            float4 a1 = *reinterpret_cast<const float4*>(&As[kk][ty*4 + 64]);
            float4 b0 = *reinterpret_cast<const float4*>(&Ws[kk][tx*4]);
            float4 b1 = *reinterpret_cast<const float4*>(&Ws[kk][tx*4 + 64]);
            float a[8] = {a0.x,a0.y,a0.z,a0.w,a1.x,a1.y,a1.z,a1.w};
            float b[8] = {b0.x,b0.y,b0.z,b0.w,b1.x,b1.y,b1.z,b1.w};
            #pragma unroll
            for (int i = 0; i < 8; ++i)
                #pragma unroll
                for (int j = 0; j < 8; ++j)
                    acc[i][j] = fmaf(a[i], b[j], acc[i][j]);
            if constexpr (DUAL) {
                float4 c0 = *reinterpret_cast<const float4*>(&As2[kk][ty*4]);
                float4 c1 = *reinterpret_cast<const float4*>(&As2[kk][ty*4 + 64]);
                float4 d0 = *reinterpret_cast<const float4*>(&Ws2[kk][tx*4]);
                float4 d1 = *reinterpret_cast<const float4*>(&Ws2[kk][tx*4 + 64]);
                float a2[8] = {c0.x,c0.y,c0.z,c0.w,c1.x,c1.y,c1.z,c1.w};
                float b2[8] = {d0.x,d0.y,d0.z,d0.w,d1.x,d1.y,d1.z,d1.w};
                #pragma unroll
                for (int i = 0; i < 8; ++i)
                    #pragma unroll
                    for (int j = 0; j < 8; ++j)
                        acc[i][j] = fmaf(a2[i], b2[j], acc[i][j]);
            }
        }
    }

    float bv[8];
    #pragma unroll
    for (int j = 0; j < 8; ++j) {
        int col = bn * 128 + tx * 4 + (j & 3) + ((j >> 2) << 6);
        bv[j] = bias1[col];
        if constexpr (DUAL) bv[j] += bias2[col];
    }
    #pragma unroll
    for (int i = 0; i < 8; ++i) {
        int r = bm * 128 + ty * 4 + (i & 3) + ((i >> 2) << 6);
        float o[8];
        #pragma unroll
        for (int j = 0; j < 8; ++j) {
            float x = acc[i][j] + bv[j];
            if constexpr (ACT == 1) x = (x >= 0.f) ? x : 0.2f * x;
            o[j] = x;
        }
        float4 w0 = {o[0], o[1], o[2], o[3]};
        float4 w1 = {o[4], o[5], o[6], o[7]};
        *reinterpret_cast<float4*>(C + (size_t)r * DM + bn * 128 + tx * 4)      = w0;
        *reinterpret_cast<float4*>(C + (size_t)r * DM + bn * 128 + tx * 4 + 64) = w1;
    }
}

// ---------------------------------------------------------------------------
// Attention: one block per (b, h, 128-row q-tile). Iterates 8 k-tiles of 128:
// S = Q@K^T (d=64 contraction), exp(relu(S/8) + mask*-1e9) -> written raw to
// att output + staged in LDS, PV accumulated in registers, row-sums tracked
// per-thread and shuffle-reduced at the end (no atomics, single writer/row).
// exp never overflows (relu'd scores are tiny); masked lanes underflow to 0,
// so no row-max pass is needed (softmax shift-invariance).
// LDS (dynamic, 136,704 B): Qt[64][132] d-major, KV union (K d-major [64][132]
// / V k-major [128][68]), Es[128][132], rsum[128].
// ---------------------------------------------------------------------------
__global__ __launch_bounds__(256) void attn_k(
    const float* __restrict__ qp, const float* __restrict__ kp,
    const float* __restrict__ vp, const float* __restrict__ mask,
    float* __restrict__ att, float* __restrict__ omid,
    float* __restrict__ rsg)
{
    extern __shared__ float sm[];
    float* Qt   = sm;                  // [64][132]
    float* KV   = sm + 64 * 132;       // K: d*132+k  |  V: k*68+d
    float* Es   = KV + 128 * 68;       // [128][132]
    float* rsum = Es + 128 * 132;      // [128] (holds 1/rowsum)

    const int t  = threadIdx.x;
    const int tx = t & 15, ty = t >> 4;
    const int blk = blockIdx.x;
    const int qt = blk & 7, h = (blk >> 3) & 15, b = blk >> 7;
    const int q0 = qt * 128;

    const size_t qbase = ((size_t)b * 1024 + q0) * DM + h * 64;
    const size_t kvbase = ((size_t)b * 1024) * DM + h * 64;
    const size_t mbase = ((size_t)b) << 20;
    const size_t abase = ((size_t)(b * 16 + h)) << 20;

    // Q tile -> Qt[d][q]
    #pragma unroll
    for (int l = 0; l < 8; ++l) {
        int f = t + l * 256;
        int r = f >> 4, dq = f & 15;
        float4 v = ldg4(qp + qbase + (size_t)r * DM + dq * 4);
        Qt[(dq*4+0)*132 + r] = v.x;
        Qt[(dq*4+1)*132 + r] = v.y;
        Qt[(dq*4+2)*132 + r] = v.z;
        Qt[(dq*4+3)*132 + r] = v.w;
    }

    float pv[8][4] = {};
    float rpart[8] = {};

    for (int kt2 = 0; kt2 < 8; ++kt2) {
        const int kb = kt2 * 128;
        __syncthreads();   // prev PV readers done (also orders Qt on iter 0)
        // K tile -> KV as Kt[d][k]
        #pragma unroll
        for (int l = 0; l < 8; ++l) {
            int f = t + l * 256;
            int r = f >> 4, dq = f & 15;
            float4 v = ldg4(kp + kvbase + (size_t)(kb + r) * DM + dq * 4);
            KV[(dq*4+0)*132 + r] = v.x;
            KV[(dq*4+1)*132 + r] = v.y;
            KV[(dq*4+2)*132 + r] = v.z;
            KV[(dq*4+3)*132 + r] = v.w;
        }
        __syncthreads();

        // scores 128x128, micro 8x8
        float s[8][8] = {};
        #pragma unroll 8
        for (int d = 0; d < 64; ++d) {
            float4 a0 = *reinterpret_cast<const float4*>(&Qt[d*132 + ty*4]);
            float4 a1 = *reinterpret_cast<const float4*>(&Qt[d*132 + ty*4 + 64]);
            float4 b0 = *reinterpret_cast<const float4*>(&KV[d*132 + tx*4]);
            float4 b1 = *reinterpret_cast<const float4*>(&KV[d*132 + tx*4 + 64]);
            float a[8] = {a0.x,a0.y,a0.z,a0.w,a1.x,a1.y,a1.z,a1.w};
            float k8[8] = {b0.x,b0.y,b0.z,b0.w,b1.x,b1.y,b1.z,b1.w};
            #pragma unroll
            for (int i = 0; i < 8; ++i)
                #pragma unroll
                for (int j = 0; j < 8; ++j)
                    s[i][j] = fmaf(a[i], k8[j], s[i][j]);
        }

        // exp(relu(s/8) + m*-1e9): write raw to att + LDS, track row-sum
        #pragma unroll
        for (int i = 0; i < 8; ++i) {
            int q  = ty * 4 + (i & 3) + ((i >> 2) << 6);
            int gq = q0 + q;
            #pragma unroll
            for (int c = 0; c < 2; ++c) {
                int kc = kb + tx * 4 + c * 64;
                float4 mv = ldg4(mask + mbase + (size_t)gq * 1024 + kc);
                float mm[4] = {mv.x, mv.y, mv.z, mv.w};
                float ov[4];
                #pragma unroll
                for (int u = 0; u < 4; ++u) {
                    float x = s[i][c*4 + u] * 0.125f;
                    x = fmaxf(x, 0.f);
                    x = fmaf(mm[u], -1.0e9f, x);
                    ov[u] = __expf(x);
                    rpart[i] += ov[u];
                }
                float4 ev = {ov[0], ov[1], ov[2], ov[3]};
                *reinterpret_cast<float4*>(att + abase + (size_t)gq * 1024 + kc) = ev;
                *reinterpret_cast<float4*>(&Es[q*132 + tx*4 + c*64]) = ev;
            }
        }
        __syncthreads();   // K reads + Es writes complete

        // V tile -> KV as Vs[k][d]
        #pragma unroll
        for (int l = 0; l < 8; ++l) {
            int f = t + l * 256;
            int r = f >> 4, dq = f & 15;
            float4 v = ldg4(vp + kvbase + (size_t)(kb + r) * DM + dq * 4);
            *reinterpret_cast<float4*>(&KV[r*68 + dq*4]) = v;
        }
        __syncthreads();

        // PV: out[q][d] += E[q][kk] * V[kk][d]
        #pragma unroll 2
        for (int kk = 0; kk < 128; kk += 4) {
            float4 ev[8];
            #pragma unroll
            for (int i = 0; i < 8; ++i) {
                int q = ty * 4 + (i & 3) + ((i >> 2) << 6);
                ev[i] = *reinterpret_cast<const float4*>(&Es[q*132 + kk]);
            }
            #pragma unroll
            for (int c = 0; c < 4; ++c) {
                float4 vv = *reinterpret_cast<const float4*>(&KV[(kk + c)*68 + tx*4]);
                #pragma unroll
                for (int i = 0; i < 8; ++i) {
                    float e = (c == 0) ? ev[i].x : (c == 1) ? ev[i].y
                            : (c == 2) ? ev[i].z : ev[i].w;
                    pv[i][0] = fmaf(e, vv.x, pv[i][0]);
                    pv[i][1] = fmaf(e, vv.y, pv[i][1]);
                    pv[i][2] = fmaf(e, vv.z, pv[i][2]);
                    pv[i][3] = fmaf(e, vv.w, pv[i][3]);
                }
            }
        }
    }

    // row-sum reduce across tx (16 lanes), single writer per row
    #pragma unroll
    for (int i = 0; i < 8; ++i) {
        float v = rpart[i];
        v += __shfl_xor(v, 1);
        v += __shfl_xor(v, 2);
        v += __shfl_xor(v, 4);
        v += __shfl_xor(v, 8);
        if (tx == 0) {
            int q = ty * 4 + (i & 3) + ((i >> 2) << 6);
            float inv = 1.f / v;
            rsum[q] = inv;
            rsg[(size_t)(b * 16 + h) * 1024 + q0 + q] = inv;
        }
    }
    __syncthreads();

    #pragma unroll
    for (int i = 0; i < 8; ++i) {
        int q = ty * 4 + (i & 3) + ((i >> 2) << 6);
        float inv = rsum[q];
        float4 o = {pv[i][0]*inv, pv[i][1]*inv, pv[i][2]*inv, pv[i][3]*inv};
        *reinterpret_cast<float4*>(
            omid + ((size_t)b * 1024 + q0 + q) * DM + h * 64 + tx * 4) = o;
    }
}

// Normalize att in place: att[row][*] *= (1/rowsum) (rsg already inverted)
__global__ __launch_bounds__(256) void norm_k(
    float* __restrict__ att, const float* __restrict__ rsg)
{
    const size_t total = (size_t)67108864 / 4;
    for (size_t i = (size_t)blockIdx.x * 256 + threadIdx.x; i < total;
         i += (size_t)gridDim.x * 256) {
        float4 v = reinterpret_cast<float4*>(att)[i];
        float s = rsg[i >> 8];
        v.x *= s; v.y *= s; v.z *= s; v.w *= s;
        reinterpret_cast<float4*>(att)[i] = v;
    }
}

extern "C" void kernel_launch(void* const* d_in, const int* in_sizes, int n_in,
                              void* d_out, int out_size, void* d_ws, size_t ws_size,
                              hipStream_t stream)
{
    const float* q    = (const float*)d_in[0];
    const float* k    = (const float*)d_in[1];
    const float* v    = (const float*)d_in[2];
    const float* e    = (const float*)d_in[3];
    const float* mask = (const float*)d_in[4];
    const float* Wq   = (const float*)d_in[5];
    const float* bq   = (const float*)d_in[6];
    const float* Wq2  = (const float*)d_in[7];
    const float* bq2  = (const float*)d_in[8];
    const float* Wq3  = (const float*)d_in[9];
    const float* bq3  = (const float*)d_in[10];
    const float* Wk   = (const float*)d_in[11];
    const float* bk   = (const float*)d_in[12];
    const float* Wk2  = (const float*)d_in[13];
    const float* bk2  = (const float*)d_in[14];
    const float* Wk3  = (const float*)d_in[15];
    const float* bk3  = (const float*)d_in[16];
    const float* Wv   = (const float*)d_in[17];
    const float* bv   = (const float*)d_in[18];
    const float* Wo   = (const float*)d_in[19];
    const float* bo   = (const float*)d_in[20];

    float* out = (float*)d_out;                         // 4096*1024
    float* att = out + (size_t)4096 * 1024;             // 65536*1024

    // workspace: 4 x 16.78 MB + rowsums = 64.3 MiB
    float* ws   = (float*)d_ws;
    float* qp   = ws;                                   // 4096*1024
    float* kp   = qp + (size_t)4096 * 1024;             // 4096*1024
    float* omid = kp + (size_t)4096 * 1024;             // 4096*1024
    float* rsg  = omid + (size_t)4096 * 1024;           // 65536
    float* tmp  = rsg + 65536;                          // 4096*1024 (reused: q-mid, k-mid, vp)

    dim3 blk(256);
    dim3 ggrid(256);

    // q path: tmp = leaky(q@Wq + bq + e@Wq2 + bq2); qp = tmp@Wq3 + bq3  (rows 1..1024)
    gemm_k<1, true ><<<ggrid, blk, 0, stream>>>(q, e, Wq, Wq2, bq, bq2, tmp, 1025, 1);
    gemm_k<0, false><<<ggrid, blk, 0, stream>>>(tmp, nullptr, Wq3, nullptr, bq3, nullptr, qp, 1024, 0);
    // k path (rows 0..1023)
    gemm_k<1, true ><<<ggrid, blk, 0, stream>>>(k, e, Wk, Wk2, bk, bk2, tmp, 1025, 0);
    gemm_k<0, false><<<ggrid, blk, 0, stream>>>(tmp, nullptr, Wk3, nullptr, bk3, nullptr, kp, 1024, 0);
    // v projection (tmp now free -> vp)
    float* vp = tmp;
    gemm_k<0, false><<<ggrid, blk, 0, stream>>>(v, nullptr, Wv, nullptr, bv, nullptr, vp, 1024, 0);

    // attention (dynamic LDS 136,704 B > 64 KB default -> raise the cap)
    size_t smem = (size_t)(64*132 + 128*68 + 128*132 + 128) * sizeof(float);
    hipFuncSetAttribute(reinterpret_cast<const void*>(attn_k),
                        hipFuncAttributeMaxDynamicSharedMemorySize, (int)smem);
    attn_k<<<dim3(512), blk, smem, stream>>>(qp, kp, vp, mask, att, omid, rsg);

    // normalize att in place (536 MB r+w, pure BW)
    norm_k<<<dim3(16384), blk, 0, stream>>>(att, rsg);

    // output projection
    gemm_k<0, false><<<ggrid, blk, 0, stream>>>(omid, nullptr, Wo, nullptr, bo, nullptr, out, 1024, 0);
}

// Round 3
// 1291.302 us; speedup vs baseline: 1.3814x; 1.3814x over previous
//
#include <hip/hip_runtime.h>

#define DM 1024
typedef unsigned short u16;
typedef __attribute__((ext_vector_type(8))) short short8;
typedef __attribute__((ext_vector_type(4))) float f32x4;

__device__ __forceinline__ float4 ldg4(const float* p) {
    return *reinterpret_cast<const float4*>(p);
}

// split f32 -> bf16 hi (truncated) + bf16 lo (residual, truncated).
// a ~= hi + lo with rel err ~2^-16.
__device__ __forceinline__ void split2(float x, u16& hi, u16& lo) {
    unsigned u = __float_as_uint(x);
    hi = (u16)(u >> 16);
    float hif = __uint_as_float(u & 0xffff0000u);
    lo = (u16)(__float_as_uint(x - hif) >> 16);
}

// ---------------------------------------------------------------------------
// Weight transpose+split: W[k][n] f32 -> Wt_hi[n][k], Wt_lo[n][k] bf16.
// 32x32 tiles via LDS. grid = (1024 tiles, 8 weights).
// ---------------------------------------------------------------------------
struct WPack {
    const float* in[8];
    u16* hi[8];
    u16* lo[8];
};

__global__ __launch_bounds__(256) void convw_k(WPack p) {
    __shared__ float T[32][33];
    const int w = blockIdx.y;
    const int tr = blockIdx.x >> 5, tc = blockIdx.x & 31;
    const int t = threadIdx.x;
    {
        int lr = t >> 3, c4 = t & 7;
        float4 v = ldg4(p.in[w] + (size_t)(tr * 32 + lr) * DM + tc * 32 + c4 * 4);
        T[lr][c4 * 4 + 0] = v.x; T[lr][c4 * 4 + 1] = v.y;
        T[lr][c4 * 4 + 2] = v.z; T[lr][c4 * 4 + 3] = v.w;
    }
    __syncthreads();
    const int n = tc * 32 + (t >> 3);
    const int kb = tr * 32 + (t & 7) * 4;
    ushort4 h4, l4;
    u16 hh, ll;
    split2(T[(t & 7) * 4 + 0][t >> 3], hh, ll); h4.x = hh; l4.x = ll;
    split2(T[(t & 7) * 4 + 1][t >> 3], hh, ll); h4.y = hh; l4.y = ll;
    split2(T[(t & 7) * 4 + 2][t >> 3], hh, ll); h4.z = hh; l4.z = ll;
    split2(T[(t & 7) * 4 + 3][t >> 3], hh, ll); h4.w = hh; l4.w = ll;
    *reinterpret_cast<ushort4*>(p.hi[w] + (size_t)n * DM + kb) = h4;
    *reinterpret_cast<ushort4*>(p.lo[w] + (size_t)n * DM + kb) = l4;
}

// ---------------------------------------------------------------------------
// Split-bf16 MFMA GEMM. C = act(A@W + b [+ A2@W2 + b2]).
// A: [4096 rows][1024] (row map: gr -> (gr>>10)*astride + (gr&1023) + aoff),
// either f32 (split on the fly) or pre-split u16 hi/lo. B: pre-transposed
// split Wt[n][k]. DUALK: K-concat [A|A2]@[W;W2], NT=64. 3 MFMA passes:
// Ah*Bh + Ah*Bl + Al*Bh (f32 accum) => ~f32 accuracy.
// Tile 128x128, BK=32, 4 waves (2x2 of 64x64), LDS dbuf 2x40960B,
// u16 row stride 40 (16B-aligned b128 frags, bank-uniform).
// One barrier/iter: write(next) -> load(kt+2) -> compute(cur) -> barrier.
// ---------------------------------------------------------------------------
template<int ACT, bool ASPLIT, bool OUTSPLIT, bool DUALK>
__global__ __launch_bounds__(256, 2) void gemm_mfma(
    const float* __restrict__ Af, const float* __restrict__ A2f,
    const u16* __restrict__ Ah, const u16* __restrict__ Al,
    const u16* __restrict__ Bh, const u16* __restrict__ Bl,
    const u16* __restrict__ B2h, const u16* __restrict__ B2l,
    const float* __restrict__ bias1, const float* __restrict__ bias2,
    float* __restrict__ Cf, u16* __restrict__ Ch, u16* __restrict__ Cl,
    int astride, int aoff)
{
    static_assert(!(ASPLIT && DUALK), "unsupported combo");
    extern __shared__ u16 lds[];
    // per-buffer u16 offsets: AsH 0, AsL 5120, BsH 10240, BsL 15360 (rows*40)
    const int t = threadIdx.x;
    const int r = t >> 1, h = t & 1;
    const int bm = blockIdx.x >> 3, bn = blockIdx.x & 7;
    const int gr = bm * 128 + r;
    const size_t arow = (size_t)(gr >> 10) * astride + (gr & 1023) + aoff;
    const size_t brow = (size_t)(bn * 128 + r);

    const int lane = t & 63, w = t >> 6;
    const int wm = w >> 1, wn = w & 1;
    const int fr = lane & 15, fk = (lane >> 4) * 8;

    constexpr int NT = DUALK ? 64 : 32;

    f32x4 acc[4][4];
    #pragma unroll
    for (int i = 0; i < 4; ++i)
        #pragma unroll
        for (int j = 0; j < 4; ++j)
            acc[i][j] = (f32x4){0.f, 0.f, 0.f, 0.f};

    uint4 ra[4];  float4 rf[4];  uint4 rb[4];

    auto LOAD = [&](int kt) {
        int kk = kt * 32 + h * 16;
        bool second = DUALK && (kk >= 1024);
        int kl = second ? kk - 1024 : kk;
        if constexpr (ASPLIT) {
            ra[0] = *reinterpret_cast<const uint4*>(Ah + arow * DM + kl);
            ra[1] = *reinterpret_cast<const uint4*>(Ah + arow * DM + kl + 8);
            ra[2] = *reinterpret_cast<const uint4*>(Al + arow * DM + kl);
            ra[3] = *reinterpret_cast<const uint4*>(Al + arow * DM + kl + 8);
        } else {
            const float* pA = second ? A2f : Af;
            #pragma unroll
            for (int c = 0; c < 4; ++c)
                rf[c] = ldg4(pA + arow * DM + kl + c * 4);
        }
        const u16* pBh = second ? B2h : Bh;
        const u16* pBl = second ? B2l : Bl;
        rb[0] = *reinterpret_cast<const uint4*>(pBh + brow * DM + kl);
        rb[1] = *reinterpret_cast<const uint4*>(pBh + brow * DM + kl + 8);
        rb[2] = *reinterpret_cast<const uint4*>(pBl + brow * DM + kl);
        rb[3] = *reinterpret_cast<const uint4*>(pBl + brow * DM + kl + 8);
    };

    auto WRITE = [&](int buf) {
        u16* base = lds + buf * 20480;
        u16* aH = base +         r * 40 + h * 16;
        u16* aL = base +  5120 + r * 40 + h * 16;
        u16* bH = base + 10240 + r * 40 + h * 16;
        u16* bL = base + 15360 + r * 40 + h * 16;
        if constexpr (ASPLIT) {
            *reinterpret_cast<uint4*>(aH) = ra[0];
            *reinterpret_cast<uint4*>(aH + 8) = ra[1];
            *reinterpret_cast<uint4*>(aL) = ra[2];
            *reinterpret_cast<uint4*>(aL + 8) = ra[3];
        } else {
            u16 hi[16], lo[16];
            float f[16] = {rf[0].x, rf[0].y, rf[0].z, rf[0].w,
                           rf[1].x, rf[1].y, rf[1].z, rf[1].w,
                           rf[2].x, rf[2].y, rf[2].z, rf[2].w,
                           rf[3].x, rf[3].y, rf[3].z, rf[3].w};
            #pragma unroll
            for (int i = 0; i < 16; ++i) split2(f[i], hi[i], lo[i]);
            #pragma unroll
            for (int q = 0; q < 2; ++q) {
                uint4 uh, ul;
                uh.x = (unsigned)hi[q*8+0] | ((unsigned)hi[q*8+1] << 16);
                uh.y = (unsigned)hi[q*8+2] | ((unsigned)hi[q*8+3] << 16);
                uh.z = (unsigned)hi[q*8+4] | ((unsigned)hi[q*8+5] << 16);
                uh.w = (unsigned)hi[q*8+6] | ((unsigned)hi[q*8+7] << 16);
                ul.x = (unsigned)lo[q*8+0] | ((unsigned)lo[q*8+1] << 16);
                ul.y = (unsigned)lo[q*8+2] | ((unsigned)lo[q*8+3] << 16);
                ul.z = (unsigned)lo[q*8+4] | ((unsigned)lo[q*8+5] << 16);
                ul.w = (unsigned)lo[q*8+6] | ((unsigned)lo[q*8+7] << 16);
                *reinterpret_cast<uint4*>(aH + q * 8) = uh;
                *reinterpret_cast<uint4*>(aL + q * 8) = ul;
            }
        }
        *reinterpret_cast<uint4*>(bH) = rb[0];
        *reinterpret_cast<uint4*>(bH + 8) = rb[1];
        *reinterpret_cast<uint4*>(bL) = rb[2];
        *reinterpret_cast<uint4*>(bL + 8) = rb[3];
    };

    auto COMPUTE = [&](int buf) {
        const u16* base = lds + buf * 20480;
        short8 ah[4], al[4];
        #pragma unroll
        for (int mi = 0; mi < 4; ++mi) {
            int ro = (wm * 64 + mi * 16 + fr) * 40 + fk;
            ah[mi] = *reinterpret_cast<const short8*>(base + ro);
            al[mi] = *reinterpret_cast<const short8*>(base + 5120 + ro);
        }
        #pragma unroll
        for (int nj = 0; nj < 4; ++nj) {
            int co = (wn * 64 + nj * 16 + fr) * 40 + fk;
            short8 bh = *reinterpret_cast<const short8*>(base + 10240 + co);
            short8 bl = *reinterpret_cast<const short8*>(base + 15360 + co);
            #pragma unroll
            for (int mi = 0; mi < 4; ++mi) {
                acc[mi][nj] = __builtin_amdgcn_mfma_f32_16x16x32_bf16(ah[mi], bh, acc[mi][nj], 0, 0, 0);
                acc[mi][nj] = __builtin_amdgcn_mfma_f32_16x16x32_bf16(ah[mi], bl, acc[mi][nj], 0, 0, 0);
                acc[mi][nj] = __builtin_amdgcn_mfma_f32_16x16x32_bf16(al[mi], bh, acc[mi][nj], 0, 0, 0);
            }
        }
    };

    LOAD(0);
    WRITE(0);
    LOAD(1);
    __syncthreads();
    for (int kt = 0; kt < NT; ++kt) {
        const int cur = kt & 1, nxt = cur ^ 1;
        if (kt + 1 < NT) WRITE(nxt);
        if (kt + 2 < NT) LOAD(kt + 2);
        COMPUTE(cur);
        __syncthreads();
    }

    // epilogue: C/D frag mapping col = lane&15, row = (lane>>4)*4 + rr (m89)
    #pragma unroll
    for (int nj = 0; nj < 4; ++nj) {
        const int col = bn * 128 + wn * 64 + nj * 16 + fr;
        float bv = bias1[col];
        if constexpr (DUALK) bv += bias2[col];
        #pragma unroll
        for (int mi = 0; mi < 4; ++mi) {
            const int row0 = bm * 128 + wm * 64 + mi * 16 + (lane >> 4) * 4;
            #pragma unroll
            for (int rr = 0; rr < 4; ++rr) {
                float x = acc[mi][nj][rr] + bv;
                if constexpr (ACT == 1) x = (x >= 0.f) ? x : 0.2f * x;
                size_t off = (size_t)(row0 + rr) * DM + col;
                if constexpr (OUTSPLIT) {
                    u16 hh, ll;
                    split2(x, hh, ll);
                    Ch[off] = hh;
                    Cl[off] = ll;
                } else {
                    Cf[off] = x;
                }
            }
        }
    }
}

// ---------------------------------------------------------------------------
// Attention (unchanged from round 1): f32 VALU, one block per (b,h,128 q-rows).
// ---------------------------------------------------------------------------
__global__ __launch_bounds__(256) void attn_k(
    const float* __restrict__ qp, const float* __restrict__ kp,
    const float* __restrict__ vp, const float* __restrict__ mask,
    float* __restrict__ att, float* __restrict__ omid,
    float* __restrict__ rsg)
{
    extern __shared__ float sm[];
    float* Qt   = sm;                  // [64][132]
    float* KV   = sm + 64 * 132;       // K: d*132+k  |  V: k*68+d
    float* Es   = KV + 128 * 68;       // [128][132]
    float* rsum = Es + 128 * 132;      // [128]

    const int t  = threadIdx.x;
    const int tx = t & 15, ty = t >> 4;
    const int blk = blockIdx.x;
    const int qt = blk & 7, hh = (blk >> 3) & 15, b = blk >> 7;
    const int q0 = qt * 128;

    const size_t qbase = ((size_t)b * 1024 + q0) * DM + hh * 64;
    const size_t kvbase = ((size_t)b * 1024) * DM + hh * 64;
    const size_t mbase = ((size_t)b) << 20;
    const size_t abase = ((size_t)(b * 16 + hh)) << 20;

    #pragma unroll
    for (int l = 0; l < 8; ++l) {
        int f = t + l * 256;
        int r = f >> 4, dq = f & 15;
        float4 v = ldg4(qp + qbase + (size_t)r * DM + dq * 4);
        Qt[(dq*4+0)*132 + r] = v.x;
        Qt[(dq*4+1)*132 + r] = v.y;
        Qt[(dq*4+2)*132 + r] = v.z;
        Qt[(dq*4+3)*132 + r] = v.w;
    }

    float pv[8][4] = {};
    float rpart[8] = {};

    for (int kt2 = 0; kt2 < 8; ++kt2) {
        const int kb = kt2 * 128;
        __syncthreads();
        #pragma unroll
        for (int l = 0; l < 8; ++l) {
            int f = t + l * 256;
            int r = f >> 4, dq = f & 15;
            float4 v = ldg4(kp + kvbase + (size_t)(kb + r) * DM + dq * 4);
            KV[(dq*4+0)*132 + r] = v.x;
            KV[(dq*4+1)*132 + r] = v.y;
            KV[(dq*4+2)*132 + r] = v.z;
            KV[(dq*4+3)*132 + r] = v.w;
        }
        __syncthreads();

        float s[8][8] = {};
        #pragma unroll 8
        for (int d = 0; d < 64; ++d) {
            float4 a0 = *reinterpret_cast<const float4*>(&Qt[d*132 + ty*4]);
            float4 a1 = *reinterpret_cast<const float4*>(&Qt[d*132 + ty*4 + 64]);
            float4 b0 = *reinterpret_cast<const float4*>(&KV[d*132 + tx*4]);
            float4 b1 = *reinterpret_cast<const float4*>(&KV[d*132 + tx*4 + 64]);
            float a[8] = {a0.x,a0.y,a0.z,a0.w,a1.x,a1.y,a1.z,a1.w};
            float k8[8] = {b0.x,b0.y,b0.z,b0.w,b1.x,b1.y,b1.z,b1.w};
            #pragma unroll
            for (int i = 0; i < 8; ++i)
                #pragma unroll
                for (int j = 0; j < 8; ++j)
                    s[i][j] = fmaf(a[i], k8[j], s[i][j]);
        }

        #pragma unroll
        for (int i = 0; i < 8; ++i) {
            int q  = ty * 4 + (i & 3) + ((i >> 2) << 6);
            int gq = q0 + q;
            #pragma unroll
            for (int c = 0; c < 2; ++c) {
                int kc = kb + tx * 4 + c * 64;
                float4 mv = ldg4(mask + mbase + (size_t)gq * 1024 + kc);
                float mm[4] = {mv.x, mv.y, mv.z, mv.w};
                float ov[4];
                #pragma unroll
                for (int u = 0; u < 4; ++u) {
                    float x = s[i][c*4 + u] * 0.125f;
                    x = fmaxf(x, 0.f);
                    x = fmaf(mm[u], -1.0e9f, x);
                    ov[u] = __expf(x);
                    rpart[i] += ov[u];
                }
                float4 ev = {ov[0], ov[1], ov[2], ov[3]};
                *reinterpret_cast<float4*>(att + abase + (size_t)gq * 1024 + kc) = ev;
                *reinterpret_cast<float4*>(&Es[q*132 + tx*4 + c*64]) = ev;
            }
        }
        __syncthreads();

        #pragma unroll
        for (int l = 0; l < 8; ++l) {
            int f = t + l * 256;
            int r = f >> 4, dq = f & 15;
            float4 v = ldg4(vp + kvbase + (size_t)(kb + r) * DM + dq * 4);
            *reinterpret_cast<float4*>(&KV[r*68 + dq*4]) = v;
        }
        __syncthreads();

        #pragma unroll 2
        for (int kk = 0; kk < 128; kk += 4) {
            float4 ev[8];
            #pragma unroll
            for (int i = 0; i < 8; ++i) {
                int q = ty * 4 + (i & 3) + ((i >> 2) << 6);
                ev[i] = *reinterpret_cast<const float4*>(&Es[q*132 + kk]);
            }
            #pragma unroll
            for (int c = 0; c < 4; ++c) {
                float4 vv = *reinterpret_cast<const float4*>(&KV[(kk + c)*68 + tx*4]);
                #pragma unroll
                for (int i = 0; i < 8; ++i) {
                    float e = (c == 0) ? ev[i].x : (c == 1) ? ev[i].y
                            : (c == 2) ? ev[i].z : ev[i].w;
                    pv[i][0] = fmaf(e, vv.x, pv[i][0]);
                    pv[i][1] = fmaf(e, vv.y, pv[i][1]);
                    pv[i][2] = fmaf(e, vv.z, pv[i][2]);
                    pv[i][3] = fmaf(e, vv.w, pv[i][3]);
                }
            }
        }
    }

    #pragma unroll
    for (int i = 0; i < 8; ++i) {
        float v = rpart[i];
        v += __shfl_xor(v, 1);
        v += __shfl_xor(v, 2);
        v += __shfl_xor(v, 4);
        v += __shfl_xor(v, 8);
        if (tx == 0) {
            int q = ty * 4 + (i & 3) + ((i >> 2) << 6);
            float inv = 1.f / v;
            rsum[q] = inv;
            rsg[(size_t)(b * 16 + hh) * 1024 + q0 + q] = inv;
        }
    }
    __syncthreads();

    #pragma unroll
    for (int i = 0; i < 8; ++i) {
        int q = ty * 4 + (i & 3) + ((i >> 2) << 6);
        float inv = rsum[q];
        float4 o = {pv[i][0]*inv, pv[i][1]*inv, pv[i][2]*inv, pv[i][3]*inv};
        *reinterpret_cast<float4*>(
            omid + ((size_t)b * 1024 + q0 + q) * DM + hh * 64 + tx * 4) = o;
    }
}

__global__ __launch_bounds__(256) void norm_k(
    float* __restrict__ att, const float* __restrict__ rsg)
{
    const size_t total = (size_t)67108864 / 4;
    for (size_t i = (size_t)blockIdx.x * 256 + threadIdx.x; i < total;
         i += (size_t)gridDim.x * 256) {
        float4 v = reinterpret_cast<float4*>(att)[i];
        float s = rsg[i >> 8];
        v.x *= s; v.y *= s; v.z *= s; v.w *= s;
        reinterpret_cast<float4*>(att)[i] = v;
    }
}

extern "C" void kernel_launch(void* const* d_in, const int* in_sizes, int n_in,
                              void* d_out, int out_size, void* d_ws, size_t ws_size,
                              hipStream_t stream)
{
    const float* q    = (const float*)d_in[0];
    const float* k    = (const float*)d_in[1];
    const float* v    = (const float*)d_in[2];
    const float* e    = (const float*)d_in[3];
    const float* mask = (const float*)d_in[4];
    const float* bq   = (const float*)d_in[6];
    const float* bq2  = (const float*)d_in[8];
    const float* bq3  = (const float*)d_in[10];
    const float* bk   = (const float*)d_in[12];
    const float* bk2  = (const float*)d_in[14];
    const float* bk3  = (const float*)d_in[16];
    const float* bv   = (const float*)d_in[18];
    const float* bo   = (const float*)d_in[20];

    float* out = (float*)d_out;                          // 4096*1024 f32
    float* att = out + (size_t)4096 * 1024;              // 65536*1024 f32

    // ws: 8 weights x (hi,lo) u16 [n][k] = 32MB, then qp/kp/vp/omid f32, rsg.
    u16* WT = (u16*)d_ws;
    const size_t WSZ = 1048576;
    float* qp   = (float*)(WT + 16 * WSZ);
    float* kp   = qp   + (size_t)4096 * 1024;
    float* vpp  = kp   + (size_t)4096 * 1024;
    float* omid = vpp  + (size_t)4096 * 1024;
    float* rsg  = omid + (size_t)4096 * 1024;

    // tmp (split intermediate) lives in the att region (dead until attn runs)
    u16* tmpH = (u16*)att;
    u16* tmpL = tmpH + (size_t)4096 * 1024;

    // weight conversion: order Wq,Wq2,Wq3,Wk,Wk2,Wk3,Wv,Wo (inputs 5,7,..,19)
    WPack wp;
    #pragma unroll
    for (int i = 0; i < 8; ++i) {
        wp.in[i] = (const float*)d_in[5 + 2 * i];
        wp.hi[i] = WT + (size_t)i * 2 * WSZ;
        wp.lo[i] = WT + (size_t)i * 2 * WSZ + WSZ;
    }
    convw_k<<<dim3(1024, 8), 256, 0, stream>>>(wp);

    auto G1 = gemm_mfma<1, false, true,  true >;  // dual f32-in, split-out, leaky
    auto G2 = gemm_mfma<0, true,  false, false>;  // split-in, f32-out
    auto GV = gemm_mfma<0, false, false, false>;  // f32-in, f32-out
    const int smemG = 81920;
    hipFuncSetAttribute((const void*)G1, hipFuncAttributeMaxDynamicSharedMemorySize, smemG);
    hipFuncSetAttribute((const void*)G2, hipFuncAttributeMaxDynamicSharedMemorySize, smemG);
    hipFuncSetAttribute((const void*)GV, hipFuncAttributeMaxDynamicSharedMemorySize, smemG);

    dim3 blk(256), grd(256);
    // q path (rows 1..1024): tmp = leaky(q@Wq+bq + e@Wq2+bq2); qp = tmp@Wq3+bq3
    G1<<<grd, blk, smemG, stream>>>(q, e, nullptr, nullptr,
        wp.hi[0], wp.lo[0], wp.hi[1], wp.lo[1], bq, bq2,
        nullptr, tmpH, tmpL, 1025, 1);
    G2<<<grd, blk, smemG, stream>>>(nullptr, nullptr, tmpH, tmpL,
        wp.hi[2], wp.lo[2], nullptr, nullptr, bq3, nullptr,
        qp, nullptr, nullptr, 1024, 0);
    // k path (rows 0..1023)
    G1<<<grd, blk, smemG, stream>>>(k, e, nullptr, nullptr,
        wp.hi[3], wp.lo[3], wp.hi[4], wp.lo[4], bk, bk2,
        nullptr, tmpH, tmpL, 1025, 0);
    G2<<<grd, blk, smemG, stream>>>(nullptr, nullptr, tmpH, tmpL,
        wp.hi[5], wp.lo[5], nullptr, nullptr, bk3, nullptr,
        kp, nullptr, nullptr, 1024, 0);
    // v projection
    GV<<<grd, blk, smemG, stream>>>(v, nullptr, nullptr, nullptr,
        wp.hi[6], wp.lo[6], nullptr, nullptr, bv, nullptr,
        vpp, nullptr, nullptr, 1024, 0);

    // attention
    const int smemA = (64*132 + 128*68 + 128*132 + 128) * 4;
    hipFuncSetAttribute((const void*)attn_k, hipFuncAttributeMaxDynamicSharedMemorySize, smemA);
    attn_k<<<dim3(512), blk, smemA, stream>>>(qp, kp, vpp, mask, att, omid, rsg);

    norm_k<<<dim3(16384), blk, 0, stream>>>(att, rsg);

    // output projection
    GV<<<grd, blk, smemG, stream>>>(omid, nullptr, nullptr, nullptr,
        wp.hi[7], wp.lo[7], nullptr, nullptr, bo, nullptr,
        out, nullptr, nullptr, 1024, 0);
}